// Round 9
// baseline (5428.701 us; speedup 1.0000x reference)
//
#include <hip/hip_runtime.h>

#define D 256
#define GBM 256          // gemm rows per block (16 waves x 16)
#define WT_PITCH 264     // bf16 elements per LDS row (256 + 8 pad)
#define BSH 9            // partition bucket shift: 512 rows per bucket
#define RPB 512          // rows per partition bucket
#define NBMAX 256        // max partition buckets (N <= 131072)
#define TILE 4096        // edges per partition block
#define CTSH 12          // col-tile shift: 4096 S-rows = 2 MB bf16 per tile
#define SBSH 7           // spmm bucket shift: 128 rows (LDS f32 acc = 128 KB)

using bf16x8 = __attribute__((ext_vector_type(8))) short;
using f32x4  = __attribute__((ext_vector_type(4))) float;

static __device__ __forceinline__ unsigned short f2bf(float f) {
    unsigned u = __builtin_bit_cast(unsigned, f);
    return (unsigned short)((u + 0x7fffu + ((u >> 16) & 1u)) >> 16);  // RNE
}
static __device__ __forceinline__ float as_f(unsigned u) {
    return __builtin_bit_cast(float, u);
}

// -------- W transpose + bf16 cast (+ zero bcounts): Wt[n][k] = bf16(W[k][n]) --------
__global__ void wt_kernel(const float* __restrict__ W, unsigned short* __restrict__ Wt,
                          int* __restrict__ bcounts, int NB) {
    int idx = blockIdx.x * blockDim.x + threadIdx.x;
    int n = idx & 255, k = idx >> 8;
    Wt[n * 256 + k] = f2bf(W[k * 256 + n]);
    if (blockIdx.x == 0 && threadIdx.x < NB) bcounts[threadIdx.x] = 0;
}

// ---------------- GEMM: S(bf16) = X @ W via MFMA, full Wt in LDS ----------------
__global__ __launch_bounds__(1024) void gemm_mfma(const float* __restrict__ X,
                                                  const unsigned short* __restrict__ Wt,
                                                  unsigned short* __restrict__ S, int N) {
    __shared__ unsigned short wlds[256 * WT_PITCH];    // 132 KB

    for (int c = threadIdx.x; c < 8192; c += 1024) {
        int n = c >> 5, kc = c & 31;
        uint4 v = *reinterpret_cast<const uint4*>(Wt + n * 256 + kc * 8);
        *reinterpret_cast<uint4*>(&wlds[n * WT_PITCH + kc * 8]) = v;
    }
    __syncthreads();

    const int lane = threadIdx.x & 63;
    const int wave = threadIdx.x >> 6;
    const int row0 = blockIdx.x * GBM + wave * 16;
    const int l16  = lane & 15;
    const int kgrp = lane >> 4;
    const int arow = min(row0 + l16, N - 1);
    const float* xp = X + (size_t)arow * 256 + kgrp * 8;

    f32x4 acc[16];
#pragma unroll
    for (int i = 0; i < 16; i++) acc[i] = (f32x4)(0.0f);

#pragma unroll
    for (int ks = 0; ks < 8; ks++) {
        float4 a0 = *reinterpret_cast<const float4*>(xp + ks * 32);
        float4 a1 = *reinterpret_cast<const float4*>(xp + ks * 32 + 4);
        bf16x8 af;
        af[0] = (short)f2bf(a0.x); af[1] = (short)f2bf(a0.y);
        af[2] = (short)f2bf(a0.z); af[3] = (short)f2bf(a0.w);
        af[4] = (short)f2bf(a1.x); af[5] = (short)f2bf(a1.y);
        af[6] = (short)f2bf(a1.z); af[7] = (short)f2bf(a1.w);
#pragma unroll
        for (int nt = 0; nt < 16; nt++) {
            bf16x8 bf = *reinterpret_cast<const bf16x8*>(
                &wlds[(nt * 16 + l16) * WT_PITCH + ks * 32 + kgrp * 8]);
            acc[nt] = __builtin_amdgcn_mfma_f32_16x16x32_bf16(af, bf, acc[nt], 0, 0, 0);
        }
    }

#pragma unroll
    for (int nt = 0; nt < 16; nt++) {
#pragma unroll
        for (int j = 0; j < 4; j++) {
            int r = row0 + kgrp * 4 + j;
            if (r < N) S[(size_t)r * 256 + nt * 16 + l16] = f2bf(acc[nt][j]);
        }
    }
}

// ---------------- bucket histogram (LDS-aggregated) ----------------
__global__ __launch_bounds__(256) void bucket_hist(const int* __restrict__ rows,
                                                   int* __restrict__ bcounts,
                                                   int E, int NB) {
    __shared__ int lh[NBMAX];
    for (int i = threadIdx.x; i < NB; i += 256) lh[i] = 0;
    __syncthreads();
    const int stride = gridDim.x * 256;
    for (int e = blockIdx.x * 256 + threadIdx.x; e < E; e += stride)
        atomicAdd(&lh[rows[e] >> BSH], 1);
    __syncthreads();
    for (int i = threadIdx.x; i < NB; i += 256) {
        int v = lh[i];
        if (v) atomicAdd(&bcounts[i], v);
    }
}

// ---------------- bucket scan (NB <= 1024, single block) ----------------
__global__ __launch_bounds__(1024) void bscan_kernel(const int* __restrict__ bcounts,
                                                     int* __restrict__ boffs,
                                                     int* __restrict__ bcursor, int NB) {
    __shared__ int wsum[16];
    const int t = threadIdx.x, lane = t & 63, w = t >> 6;
    int x = (t < NB) ? bcounts[t] : 0;
    int s = x;
#pragma unroll
    for (int d = 1; d < 64; d <<= 1) {
        int y = __shfl_up(s, d);
        if (lane >= d) s += y;
    }
    if (lane == 63) wsum[w] = s;
    __syncthreads();
    if (w == 0) {
        int ws = (lane < 16) ? wsum[lane] : 0;
#pragma unroll
        for (int d = 1; d < 16; d <<= 1) {
            int y = __shfl_up(ws, d);
            if (lane >= d) ws += y;
        }
        if (lane < 16) wsum[lane] = ws;
    }
    __syncthreads();
    int excl = (w ? wsum[w - 1] : 0) + s - x;
    if (t < NB) { boffs[t] = excl; bcursor[t] = excl; }
}

// ---------------- partition: per-block bulk reservation, rank in LDS ----------------
__global__ __launch_bounds__(256) void partition_kernel(const int* __restrict__ rows,
                                                        const int* __restrict__ cols,
                                                        const float* __restrict__ vals,
                                                        int* __restrict__ bcursor,
                                                        int2* __restrict__ packed,
                                                        int E, int NB) {
    __shared__ int lh[NBMAX];
    __shared__ int gbase[NBMAX];
    const int t = threadIdx.x;
    const int e0 = blockIdx.x * TILE;

    for (int i = t; i < NB; i += 256) lh[i] = 0;
    __syncthreads();

    int bk[16], rk[16], pc[16], pv[16];
#pragma unroll
    for (int j = 0; j < 16; j++) {
        int idx = e0 + j * 256 + t;
        if (idx < E) {
            int r = rows[idx];
            bk[j] = r >> BSH;
            rk[j] = atomicAdd(&lh[bk[j]], 1);
            pc[j] = ((r & (RPB - 1)) << 17) | cols[idx];
            pv[j] = __float_as_int(vals[idx]);
        } else {
            bk[j] = -1;
        }
    }
    __syncthreads();

    for (int i = t; i < NB; i += 256) {
        int c = lh[i];
        gbase[i] = c ? atomicAdd(&bcursor[i], c) : 0;
    }
    __syncthreads();

#pragma unroll
    for (int j = 0; j < 16; j++) {
        if (bk[j] >= 0) {
            int2 p; p.x = pc[j]; p.y = pv[j];
            packed[(size_t)gbase[bk[j]] + rk[j]] = p;
        }
    }
}

// ------- sort_tiles: per 512-bucket counting sort by (sub-bucket, col-tile) -------
// key = (lr9>>7)*NT + (col>>CTSH), <= 4*32 = 128 keys. Writes stay in the bucket's
// contiguous ~130 KB region (L2-local). Emits bofs2 (sub-bucket starts).
__global__ __launch_bounds__(1024) void sort_tiles(const int2* __restrict__ packed,
                                                   const int* __restrict__ boffs,
                                                   const int* __restrict__ bcounts,
                                                   int2* __restrict__ packed2,
                                                   int* __restrict__ bofs2,
                                                   int E, int NT) {
    __shared__ int cnt[128];
    __shared__ int cur[128];
    const int b = blockIdx.x, t = threadIdx.x;
    const int base = boffs[b], nb = bcounts[b];
    const int nkey = 4 * NT;

    if (t < nkey) cnt[t] = 0;
    __syncthreads();
    for (int i = t; i < nb; i += 1024) {
        int px = packed[base + i].x;
        int key = ((px >> 24) & 3) * NT + ((px & 0x1FFFF) >> CTSH);
        atomicAdd(&cnt[key], 1);
    }
    __syncthreads();
    if (t == 0) {
        int run = 0;
        for (int k = 0; k < nkey; k++) { cur[k] = run; run += cnt[k]; }
#pragma unroll
        for (int s = 0; s < 4; s++) bofs2[b * 4 + s] = base + cur[s * NT];
        if (b == gridDim.x - 1) bofs2[gridDim.x * 4] = E;   // sentinel
    }
    __syncthreads();
    for (int i = t; i < nb; i += 1024) {
        int2 p = packed[base + i];
        int key = ((p.x >> 24) & 3) * NT + ((p.x & 0x1FFFF) >> CTSH);
        int pos = base + atomicAdd(&cur[key], 1);
        int2 o;
        o.x = p.x & 0x00FFFFFF;   // keep lr7 (bits 17..23) + col (bits 0..16)
        o.y = p.y;
        packed2[pos] = o;
    }
}

// ------- SpMM: 128-row bucket, LDS f32 accumulator, edge-parallel, tile-sorted -------
// acc layout swizzled: acc[lr*256 + k*64 + lane] holds col lane*4+k  (bank = lane%32).
__global__ __launch_bounds__(1024) void spmm_lds(const unsigned short* __restrict__ S,
                                                 const int* __restrict__ bofs2,
                                                 const int2* __restrict__ packed2,
                                                 const float* __restrict__ bias,
                                                 float* __restrict__ out, int N) {
    __shared__ float acc[128 * 256];   // 128 KB
    const int t = threadIdx.x, lane = t & 63, wave = t >> 6;
    const int b = blockIdx.x;
    const int estart = bofs2[b], eend = bofs2[b + 1];

    for (int i = t; i < 32768; i += 1024) acc[i] = 0.f;
    __syncthreads();

    const char* Sb = reinterpret_cast<const char*>(S);
    const int laneoff = lane << 3;     // 8 B of the 512 B S row per lane

    for (int i0 = estart + wave * 64; i0 < eend; i0 += 1024) {
        int idx = i0 + lane;
        int2 p = (idx < eend) ? packed2[idx] : int2{0, 0};
        const int cnt = min(64, eend - i0);
        for (int j = 0; j < cnt; j++) {
            int px = __builtin_amdgcn_readlane(p.x, j);          // SGPR broadcast
            float v = as_f((unsigned)__builtin_amdgcn_readlane(p.y, j));
            int col = px & 0x1FFFF;
            int lr  = (px >> 17) & 127;
            uint2 sv = *reinterpret_cast<const uint2*>(
                Sb + ((size_t)col << 9) + laneoff);              // coalesced 512 B row
            float* a = acc + (lr << 8) + lane;
            atomicAdd(a,       v * as_f(sv.x << 16));            // ds_add_f32, bank-free
            atomicAdd(a + 64,  v * as_f(sv.x & 0xffff0000u));
            atomicAdd(a + 128, v * as_f(sv.y << 16));
            atomicAdd(a + 192, v * as_f(sv.y & 0xffff0000u));
        }
    }
    __syncthreads();

    // write out + bias: col l6*4+k <- acc[lr*256 + k*64 + l6]
    const int l6 = t & 63, grp = t >> 6;
    const int r0 = b << SBSH;
    float4 b4 = reinterpret_cast<const float4*>(bias)[l6];
#pragma unroll
    for (int s = 0; s < 8; s++) {
        int lr = grp * 8 + s;
        int r = r0 + lr;
        if (r < N) {
            float4 o;
            o.x = acc[(lr << 8) + l6]       + b4.x;
            o.y = acc[(lr << 8) + 64 + l6]  + b4.y;
            o.z = acc[(lr << 8) + 128 + l6] + b4.z;
            o.w = acc[(lr << 8) + 192 + l6] + b4.w;
            reinterpret_cast<float4*>(out)[(size_t)r * 64 + l6] = o;
        }
    }
}

extern "C" void kernel_launch(void* const* d_in, const int* in_sizes, int n_in,
                              void* d_out, int out_size, void* d_ws, size_t ws_size,
                              hipStream_t stream) {
    const float* X     = (const float*)d_in[0];
    const float* W     = (const float*)d_in[1];
    const float* bias  = (const float*)d_in[2];
    const float* evals = (const float*)d_in[3];
    const int*   erow  = (const int*)d_in[4];
    const int*   ecol  = (const int*)d_in[5];
    float* out = (float*)d_out;

    const int N = in_sizes[0] / D;
    const int E = in_sizes[3];
    const int NB = ((N - 1) >> BSH) + 1;            // 512-row partition buckets
    const int NT = ((N - 1) >> CTSH) + 1;           // 2 MB col-tiles
    const int NB2 = NB * 4;                         // 128-row spmm buckets

    char* ws = (char*)d_ws;
    size_t off = 0;
    auto alloc = [&](size_t bytes) {
        void* p = ws + off;
        off += (bytes + 255) & ~(size_t)255;
        return p;
    };
    unsigned short* S  = (unsigned short*)alloc((size_t)N * D * sizeof(unsigned short));
    unsigned short* Wt = (unsigned short*)alloc((size_t)D * D * sizeof(unsigned short));
    int* bcounts = (int*)alloc((size_t)NB * sizeof(int));
    int* boffs   = (int*)alloc((size_t)NB * sizeof(int));
    int* bcursor = (int*)alloc((size_t)NB * sizeof(int));
    int* bofs2   = (int*)alloc((size_t)(NB2 + 1) * sizeof(int));
    int2* packed  = (int2*)alloc((size_t)E * sizeof(int2));
    int2* packed2 = (int2*)alloc((size_t)E * sizeof(int2));

    // 1. Wt = bf16(W^T), zero bcounts
    wt_kernel<<<(D * D) / 256, 256, 0, stream>>>(W, Wt, bcounts, NB);
    // 2. S = bf16(X @ W) via MFMA
    gemm_mfma<<<(N + GBM - 1) / GBM, 1024, 0, stream>>>(X, Wt, S, N);
    // 3. CSR build: bucket partition, then (sub-bucket, col-tile) counting sort
    bucket_hist<<<1024, 256, 0, stream>>>(erow, bcounts, E, NB);
    bscan_kernel<<<1, 1024, 0, stream>>>(bcounts, boffs, bcursor, NB);
    partition_kernel<<<(E + TILE - 1) / TILE, 256, 0, stream>>>(erow, ecol, evals, bcursor,
                                                                packed, E, NB);
    sort_tiles<<<NB, 1024, 0, stream>>>(packed, boffs, bcounts, packed2, bofs2, E, NT);
    // 4. SpMM + bias: LDS-accumulated, tile-swept
    spmm_lds<<<NB2, 1024, 0, stream>>>(S, bofs2, packed2, bias, out, N);
}

// Round 10
// 470.661 us; speedup vs baseline: 11.5342x; 11.5342x over previous
//
#include <hip/hip_runtime.h>

#define D 256
#define WT_PITCH 264     // (unused in no-LDS gemm, kept for reference)
#define BSH 9            // bucket shift: 512 rows per bucket
#define RPB 512          // rows per bucket
#define NBMAX 256        // max buckets (N <= 131072)
#define TILE 4096        // edges per partition block

using bf16x8 = __attribute__((ext_vector_type(8))) short;
using f32x4  = __attribute__((ext_vector_type(4))) float;

static __device__ __forceinline__ unsigned short f2bf(float f) {
    unsigned u = __builtin_bit_cast(unsigned, f);
    return (unsigned short)((u + 0x7fffu + ((u >> 16) & 1u)) >> 16);  // RNE
}
static __device__ __forceinline__ float as_f(unsigned u) {
    return __builtin_bit_cast(float, u);
}

// -------- W transpose + bf16 cast (+ zero bcounts): Wt[n][k] = bf16(W[k][n]) --------
__global__ void wt_kernel(const float* __restrict__ W, unsigned short* __restrict__ Wt,
                          int* __restrict__ bcounts, int NB) {
    int idx = blockIdx.x * blockDim.x + threadIdx.x;
    int n = idx & 255, k = idx >> 8;
    Wt[n * 256 + k] = f2bf(W[k * 256 + n]);
    if (blockIdx.x == 0 && threadIdx.x < NB) bcounts[threadIdx.x] = 0;
}

// ------- GEMM: S(bf16) = X @ W via MFMA, B-fragments direct from L2 (no LDS) -------
// Wt is 128 KB -> L2-resident; each wave B-load covers 16 full 64 B lines.
__global__ __launch_bounds__(256) void gemm_mfma(const float* __restrict__ X,
                                                 const unsigned short* __restrict__ Wt,
                                                 unsigned short* __restrict__ S, int N) {
    const int lane = threadIdx.x & 63;
    const int wave = threadIdx.x >> 6;
    const int row0 = blockIdx.x * 64 + wave * 16;
    const int l16  = lane & 15;
    const int kgrp = lane >> 4;
    const int arow = min(row0 + l16, N - 1);
    const float* xp = X + (size_t)arow * 256 + kgrp * 8;
    const unsigned short* wp = Wt + l16 * 256 + kgrp * 8;

    f32x4 acc[16];
#pragma unroll
    for (int i = 0; i < 16; i++) acc[i] = (f32x4)(0.0f);

#pragma unroll
    for (int ks = 0; ks < 8; ks++) {
        float4 a0 = *reinterpret_cast<const float4*>(xp + ks * 32);
        float4 a1 = *reinterpret_cast<const float4*>(xp + ks * 32 + 4);
        bf16x8 af;
        af[0] = (short)f2bf(a0.x); af[1] = (short)f2bf(a0.y);
        af[2] = (short)f2bf(a0.z); af[3] = (short)f2bf(a0.w);
        af[4] = (short)f2bf(a1.x); af[5] = (short)f2bf(a1.y);
        af[6] = (short)f2bf(a1.z); af[7] = (short)f2bf(a1.w);
#pragma unroll
        for (int nt = 0; nt < 16; nt++) {
            bf16x8 bf = *reinterpret_cast<const bf16x8*>(
                wp + nt * 16 * 256 + ks * 32);
            acc[nt] = __builtin_amdgcn_mfma_f32_16x16x32_bf16(af, bf, acc[nt], 0, 0, 0);
        }
    }

    // C/D layout: col = lane&15, row = (lane>>4)*4 + reg
#pragma unroll
    for (int nt = 0; nt < 16; nt++) {
#pragma unroll
        for (int j = 0; j < 4; j++) {
            int r = row0 + kgrp * 4 + j;
            if (r < N) S[(size_t)r * 256 + nt * 16 + l16] = f2bf(acc[nt][j]);
        }
    }
}

// ---------------- bucket histogram (LDS-aggregated) ----------------
__global__ __launch_bounds__(256) void bucket_hist(const int* __restrict__ rows,
                                                   int* __restrict__ bcounts,
                                                   int E, int NB) {
    __shared__ int lh[NBMAX];
    for (int i = threadIdx.x; i < NB; i += 256) lh[i] = 0;
    __syncthreads();
    const int stride = gridDim.x * 256;
    for (int e = blockIdx.x * 256 + threadIdx.x; e < E; e += stride)
        atomicAdd(&lh[rows[e] >> BSH], 1);
    __syncthreads();
    for (int i = threadIdx.x; i < NB; i += 256) {
        int v = lh[i];
        if (v) atomicAdd(&bcounts[i], v);
    }
}

// ---------------- bucket scan (NB <= 1024, single block) ----------------
__global__ __launch_bounds__(1024) void bscan_kernel(const int* __restrict__ bcounts,
                                                     int* __restrict__ boffs,
                                                     int* __restrict__ bcursor, int NB) {
    __shared__ int wsum[16];
    const int t = threadIdx.x, lane = t & 63, w = t >> 6;
    int x = (t < NB) ? bcounts[t] : 0;
    int s = x;
#pragma unroll
    for (int d = 1; d < 64; d <<= 1) {
        int y = __shfl_up(s, d);
        if (lane >= d) s += y;
    }
    if (lane == 63) wsum[w] = s;
    __syncthreads();
    if (w == 0) {
        int ws = (lane < 16) ? wsum[lane] : 0;
#pragma unroll
        for (int d = 1; d < 16; d <<= 1) {
            int y = __shfl_up(ws, d);
            if (lane >= d) ws += y;
        }
        if (lane < 16) wsum[lane] = ws;
    }
    __syncthreads();
    int excl = (w ? wsum[w - 1] : 0) + s - x;
    if (t < NB) { boffs[t] = excl; bcursor[t] = excl; }
}

// ---------------- partition: per-block bulk reservation, rank in LDS ----------------
__global__ __launch_bounds__(256) void partition_kernel(const int* __restrict__ rows,
                                                        const int* __restrict__ cols,
                                                        const float* __restrict__ vals,
                                                        int* __restrict__ bcursor,
                                                        int2* __restrict__ packed,
                                                        int E, int NB) {
    __shared__ int lh[NBMAX];
    __shared__ int gbase[NBMAX];
    const int t = threadIdx.x;
    const int e0 = blockIdx.x * TILE;

    for (int i = t; i < NB; i += 256) lh[i] = 0;
    __syncthreads();

    int bk[16], rk[16], pc[16], pv[16];
#pragma unroll
    for (int j = 0; j < 16; j++) {
        int idx = e0 + j * 256 + t;
        if (idx < E) {
            int r = rows[idx];
            bk[j] = r >> BSH;
            rk[j] = atomicAdd(&lh[bk[j]], 1);
            pc[j] = ((r & (RPB - 1)) << 17) | cols[idx];
            pv[j] = __float_as_int(vals[idx]);
        } else {
            bk[j] = -1;
        }
    }
    __syncthreads();

    for (int i = t; i < NB; i += 256) {
        int c = lh[i];
        gbase[i] = c ? atomicAdd(&bcursor[i], c) : 0;
    }
    __syncthreads();

#pragma unroll
    for (int j = 0; j < 16; j++) {
        if (bk[j] >= 0) {
            int2 p; p.x = pc[j]; p.y = pv[j];
            packed[(size_t)gbase[bk[j]] + rk[j]] = p;
        }
    }
}

// ------- per-bucket counting sort by localrow -> CSR (+offs/counts), 1024 thr -------
__global__ __launch_bounds__(1024) void bucket_scatter(const int2* __restrict__ packed,
                                                       const int* __restrict__ boffs,
                                                       const int* __restrict__ bcounts,
                                                       int* __restrict__ offs,
                                                       int* __restrict__ counts,
                                                       int2* __restrict__ cv, int N) {
    __shared__ int cnt[RPB];
    __shared__ int lofs[RPB];
    __shared__ int wsum[16];
    const int b = blockIdx.x, t = threadIdx.x;
    const int base = boffs[b], nb = bcounts[b];
    const int lane = t & 63, w = t >> 6;

    for (int i = t; i < RPB; i += 1024) cnt[i] = 0;
    __syncthreads();
    for (int i = t; i < nb; i += 1024)
        atomicAdd(&cnt[((unsigned)packed[base + i].x) >> 17], 1);
    __syncthreads();

    // exclusive scan over 512 counters, one per thread (t < 512)
    int x = (t < RPB) ? cnt[t] : 0;
    int s = x;
#pragma unroll
    for (int d = 1; d < 64; d <<= 1) {
        int y = __shfl_up(s, d);
        if (lane >= d) s += y;
    }
    if (lane == 63) wsum[w] = s;
    __syncthreads();
    if (w == 0) {
        int ws = (lane < 16) ? wsum[lane] : 0;
#pragma unroll
        for (int d = 1; d < 16; d <<= 1) {
            int y = __shfl_up(ws, d);
            if (lane >= d) ws += y;
        }
        if (lane < 16) wsum[lane] = ws;
    }
    __syncthreads();
    int excl = (w ? wsum[w - 1] : 0) + s - x;

    const int r0 = b << BSH;
    if (t < RPB) {
        int r = r0 + t;
        if (r < N) { offs[r] = base + excl; counts[r] = x; }
        lofs[t] = excl;
    }
    __syncthreads();

    for (int i = t; i < nb; i += 1024) {
        int2 p = packed[base + i];
        int lr = ((unsigned)p.x) >> 17;
        int pos = base + atomicAdd(&lofs[lr], 1);
        int2 o;
        o.x = p.x & 0x1FFFF;
        o.y = p.y;
        cv[pos] = o;
    }
}

// ------- SpMM: wave per row, 8-wide unrolled bf16 gathers (R6, proven 222 us) -------
__global__ __launch_bounds__(256) void spmm_kernel(const unsigned short* __restrict__ S,
                                                   const int* __restrict__ offs,
                                                   const int* __restrict__ counts,
                                                   const int2* __restrict__ cv,
                                                   const float* __restrict__ bias,
                                                   float* __restrict__ out, int N) {
    const int lane = threadIdx.x & 63;
    const int r = blockIdx.x * 4 + (threadIdx.x >> 6);
    if (r >= N) return;
    const char* Sb = reinterpret_cast<const char*>(S);

    float4 acc = { 0.f, 0.f, 0.f, 0.f };
    int i = offs[r];
    const int end = i + counts[r];

#define GATHER(c, v)                                                              \
    {                                                                             \
        uint2 sv = *reinterpret_cast<const uint2*>(Sb + ((size_t)(c) << 9) + (lane << 3)); \
        acc.x += (v) * as_f(sv.x << 16);                                          \
        acc.y += (v) * as_f(sv.x & 0xffff0000u);                                  \
        acc.z += (v) * as_f(sv.y << 16);                                          \
        acc.w += (v) * as_f(sv.y & 0xffff0000u);                                  \
    }

    for (; i + 7 < end; i += 8) {
        int2 e0 = cv[i],     e1 = cv[i + 1], e2 = cv[i + 2], e3 = cv[i + 3];
        int2 e4 = cv[i + 4], e5 = cv[i + 5], e6 = cv[i + 6], e7 = cv[i + 7];
        GATHER(e0.x, as_f((unsigned)e0.y));
        GATHER(e1.x, as_f((unsigned)e1.y));
        GATHER(e2.x, as_f((unsigned)e2.y));
        GATHER(e3.x, as_f((unsigned)e3.y));
        GATHER(e4.x, as_f((unsigned)e4.y));
        GATHER(e5.x, as_f((unsigned)e5.y));
        GATHER(e6.x, as_f((unsigned)e6.y));
        GATHER(e7.x, as_f((unsigned)e7.y));
    }
    for (; i + 1 < end; i += 2) {
        int2 e0 = cv[i], e1 = cv[i + 1];
        GATHER(e0.x, as_f((unsigned)e0.y));
        GATHER(e1.x, as_f((unsigned)e1.y));
    }
    if (i < end) {
        int2 e0 = cv[i];
        GATHER(e0.x, as_f((unsigned)e0.y));
    }
#undef GATHER

    float4 b = reinterpret_cast<const float4*>(bias)[lane];
    float4 o = { acc.x + b.x, acc.y + b.y, acc.z + b.z, acc.w + b.w };
    reinterpret_cast<float4*>(out)[(size_t)r * 64 + lane] = o;
}

extern "C" void kernel_launch(void* const* d_in, const int* in_sizes, int n_in,
                              void* d_out, int out_size, void* d_ws, size_t ws_size,
                              hipStream_t stream) {
    const float* X     = (const float*)d_in[0];
    const float* W     = (const float*)d_in[1];
    const float* bias  = (const float*)d_in[2];
    const float* evals = (const float*)d_in[3];
    const int*   erow  = (const int*)d_in[4];
    const int*   ecol  = (const int*)d_in[5];
    float* out = (float*)d_out;

    const int N = in_sizes[0] / D;
    const int E = in_sizes[3];
    const int NB = ((N - 1) >> BSH) + 1;

    char* ws = (char*)d_ws;
    size_t off = 0;
    auto alloc = [&](size_t bytes) {
        void* p = ws + off;
        off += (bytes + 255) & ~(size_t)255;
        return p;
    };
    unsigned short* S  = (unsigned short*)alloc((size_t)N * D * sizeof(unsigned short));
    unsigned short* Wt = (unsigned short*)alloc((size_t)D * D * sizeof(unsigned short));
    int* bcounts = (int*)alloc((size_t)NB * sizeof(int));
    int* boffs   = (int*)alloc((size_t)NB * sizeof(int));
    int* bcursor = (int*)alloc((size_t)NB * sizeof(int));
    int* offs    = (int*)alloc((size_t)N * sizeof(int));
    int* counts  = (int*)alloc((size_t)N * sizeof(int));
    int2* packed = (int2*)alloc((size_t)E * sizeof(int2));
    int2* cv     = (int2*)alloc((size_t)E * sizeof(int2));

    // 1. Wt = bf16(W^T), zero bcounts
    wt_kernel<<<(D * D) / 256, 256, 0, stream>>>(W, Wt, bcounts, NB);
    // 2. S = bf16(X @ W) via MFMA (B direct from L2, no LDS)
    gemm_mfma<<<(N + 63) / 64, 256, 0, stream>>>(X, Wt, S, N);
    // 3. two-phase CSR build
    bucket_hist<<<1024, 256, 0, stream>>>(erow, bcounts, E, NB);
    bscan_kernel<<<1, 1024, 0, stream>>>(bcounts, boffs, bcursor, NB);
    partition_kernel<<<(E + TILE - 1) / TILE, 256, 0, stream>>>(erow, ecol, evals, bcursor,
                                                                packed, E, NB);
    bucket_scatter<<<NB, 1024, 0, stream>>>(packed, boffs, bcounts, offs, counts, cv, N);
    // 4. SpMM + bias (R6 flat loop, 8 gathers in flight)
    spmm_kernel<<<(N + 3) / 4, 256, 0, stream>>>(S, offs, counts, cv, bias, out, N);
}

// Round 11
// 379.621 us; speedup vs baseline: 14.3003x; 1.2398x over previous
//
#include <hip/hip_runtime.h>

#define D 256
#define GBM 256          // gemm rows per block (16 waves x 16)
#define WT_PITCH 264     // bf16 elements per LDS row (256 + 8 pad)
#define BSH 9            // bucket shift: 512 rows per bucket
#define RPB 512          // rows per bucket
#define NBMAX 256        // max buckets (N <= 131072)
#define TILE 4096        // edges per partition block

using bf16x8 = __attribute__((ext_vector_type(8))) short;
using f32x4  = __attribute__((ext_vector_type(4))) float;

static __device__ __forceinline__ unsigned short f2bf(float f) {
    unsigned u = __builtin_bit_cast(unsigned, f);
    return (unsigned short)((u + 0x7fffu + ((u >> 16) & 1u)) >> 16);  // RNE
}
static __device__ __forceinline__ float as_f(unsigned u) {
    return __builtin_bit_cast(float, u);
}

// -------- W transpose + bf16 cast (+ zero bcounts): Wt[n][k] = bf16(W[k][n]) --------
__global__ void wt_kernel(const float* __restrict__ W, unsigned short* __restrict__ Wt,
                          int* __restrict__ bcounts, int NB) {
    int idx = blockIdx.x * blockDim.x + threadIdx.x;
    int n = idx & 255, k = idx >> 8;
    Wt[n * 256 + k] = f2bf(W[k * 256 + n]);
    if (blockIdx.x == 0 && threadIdx.x < NB) bcounts[threadIdx.x] = 0;
}

// ---- GEMM: S(bf16) = X @ W via MFMA, full Wt in LDS; bucket histogram fused ----
__global__ __launch_bounds__(1024) void gemm_mfma(const float* __restrict__ X,
                                                  const unsigned short* __restrict__ Wt,
                                                  unsigned short* __restrict__ S, int N,
                                                  const int* __restrict__ erow,
                                                  int* __restrict__ bcounts,
                                                  int E, int NB) {
    __shared__ unsigned short wlds[256 * WT_PITCH];    // 132 KB
    __shared__ int lh[NBMAX];                          // +1 KB for fused hist

    for (int c = threadIdx.x; c < 8192; c += 1024) {
        int n = c >> 5, kc = c & 31;
        uint4 v = *reinterpret_cast<const uint4*>(Wt + n * 256 + kc * 8);
        *reinterpret_cast<uint4*>(&wlds[n * WT_PITCH + kc * 8]) = v;
    }
    for (int i = threadIdx.x; i < NB; i += 1024) lh[i] = 0;
    __syncthreads();

    const int lane = threadIdx.x & 63;
    const int wave = threadIdx.x >> 6;
    const int row0 = blockIdx.x * GBM + wave * 16;
    const int l16  = lane & 15;
    const int kgrp = lane >> 4;
    const int arow = min(row0 + l16, N - 1);
    const float* xp = X + (size_t)arow * 256 + kgrp * 8;

    f32x4 acc[16];
#pragma unroll
    for (int i = 0; i < 16; i++) acc[i] = (f32x4)(0.0f);

#pragma unroll
    for (int ks = 0; ks < 8; ks++) {
        f32x4 a0 = __builtin_nontemporal_load(reinterpret_cast<const f32x4*>(xp + ks * 32));
        f32x4 a1 = __builtin_nontemporal_load(reinterpret_cast<const f32x4*>(xp + ks * 32 + 4));
        bf16x8 af;
        af[0] = (short)f2bf(a0[0]); af[1] = (short)f2bf(a0[1]);
        af[2] = (short)f2bf(a0[2]); af[3] = (short)f2bf(a0[3]);
        af[4] = (short)f2bf(a1[0]); af[5] = (short)f2bf(a1[1]);
        af[6] = (short)f2bf(a1[2]); af[7] = (short)f2bf(a1[3]);
#pragma unroll
        for (int nt = 0; nt < 16; nt++) {
            bf16x8 bf = *reinterpret_cast<const bf16x8*>(
                &wlds[(nt * 16 + l16) * WT_PITCH + ks * 32 + kgrp * 8]);
            acc[nt] = __builtin_amdgcn_mfma_f32_16x16x32_bf16(af, bf, acc[nt], 0, 0, 0);
        }
    }

    // C/D layout: col = lane&15, row = (lane>>4)*4 + reg
#pragma unroll
    for (int nt = 0; nt < 16; nt++) {
#pragma unroll
        for (int j = 0; j < 4; j++) {
            int r = row0 + kgrp * 4 + j;
            if (r < N) S[(size_t)r * 256 + nt * 16 + l16] = f2bf(acc[nt][j]);
        }
    }

    // ---- fused bucket histogram (hidden under gemm's memory phase) ----
    const int stride = gridDim.x * 1024;
    for (int e = blockIdx.x * 1024 + threadIdx.x; e < E; e += stride)
        atomicAdd(&lh[erow[e] >> BSH], 1);
    __syncthreads();
    for (int i = threadIdx.x; i < NB; i += 1024) {
        int v = lh[i];
        if (v) atomicAdd(&bcounts[i], v);
    }
}

// ---------------- bucket scan (NB <= 1024, single block) ----------------
__global__ __launch_bounds__(1024) void bscan_kernel(const int* __restrict__ bcounts,
                                                     int* __restrict__ boffs,
                                                     int* __restrict__ bcursor, int NB) {
    __shared__ int wsum[16];
    const int t = threadIdx.x, lane = t & 63, w = t >> 6;
    int x = (t < NB) ? bcounts[t] : 0;
    int s = x;
#pragma unroll
    for (int d = 1; d < 64; d <<= 1) {
        int y = __shfl_up(s, d);
        if (lane >= d) s += y;
    }
    if (lane == 63) wsum[w] = s;
    __syncthreads();
    if (w == 0) {
        int ws = (lane < 16) ? wsum[lane] : 0;
#pragma unroll
        for (int d = 1; d < 16; d <<= 1) {
            int y = __shfl_up(ws, d);
            if (lane >= d) ws += y;
        }
        if (lane < 16) wsum[lane] = ws;
    }
    __syncthreads();
    int excl = (w ? wsum[w - 1] : 0) + s - x;
    if (t < NB) { boffs[t] = excl; bcursor[t] = excl; }
}

// ---------------- partition: per-block bulk reservation, rank in LDS ----------------
__global__ __launch_bounds__(256) void partition_kernel(const int* __restrict__ rows,
                                                        const int* __restrict__ cols,
                                                        const float* __restrict__ vals,
                                                        int* __restrict__ bcursor,
                                                        int2* __restrict__ packed,
                                                        int E, int NB) {
    __shared__ int lh[NBMAX];
    __shared__ int gbase[NBMAX];
    const int t = threadIdx.x;
    const int e0 = blockIdx.x * TILE;

    for (int i = t; i < NB; i += 256) lh[i] = 0;
    __syncthreads();

    int bk[16], rk[16], pc[16], pv[16];
#pragma unroll
    for (int j = 0; j < 16; j++) {
        int idx = e0 + j * 256 + t;
        if (idx < E) {
            int r = rows[idx];
            bk[j] = r >> BSH;
            rk[j] = atomicAdd(&lh[bk[j]], 1);
            pc[j] = ((r & (RPB - 1)) << 17) | cols[idx];
            pv[j] = __float_as_int(vals[idx]);
        } else {
            bk[j] = -1;
        }
    }
    __syncthreads();

    for (int i = t; i < NB; i += 256) {
        int c = lh[i];
        gbase[i] = c ? atomicAdd(&bcursor[i], c) : 0;
    }
    __syncthreads();

#pragma unroll
    for (int j = 0; j < 16; j++) {
        if (bk[j] >= 0) {
            int2 p; p.x = pc[j]; p.y = pv[j];
            packed[(size_t)gbase[bk[j]] + rk[j]] = p;
        }
    }
}

// ------- per-bucket counting sort by localrow -> CSR (+offs/counts) -------
__global__ __launch_bounds__(256) void bucket_scatter(const int2* __restrict__ packed,
                                                      const int* __restrict__ boffs,
                                                      const int* __restrict__ bcounts,
                                                      int* __restrict__ offs,
                                                      int* __restrict__ counts,
                                                      int2* __restrict__ cv, int N) {
    __shared__ int cnt[RPB];
    __shared__ int lofs[RPB];
    __shared__ int wsum[4];
    const int b = blockIdx.x, t = threadIdx.x;
    const int base = boffs[b], nb = bcounts[b];
    const int lane = t & 63, w = t >> 6;

    for (int i = t; i < RPB; i += 256) cnt[i] = 0;
    __syncthreads();
    for (int i = t; i < nb; i += 256)
        atomicAdd(&cnt[((unsigned)packed[base + i].x) >> 17], 1);
    __syncthreads();

    // exclusive scan over 512 counters: 2 per thread + wave scan
    int a0 = cnt[2 * t], a1 = cnt[2 * t + 1];
    int s = a0 + a1;
    int ss = s;
#pragma unroll
    for (int d = 1; d < 64; d <<= 1) {
        int y = __shfl_up(ss, d);
        if (lane >= d) ss += y;
    }
    if (lane == 63) wsum[w] = ss;
    __syncthreads();
    int wex = 0;
    if (w > 0) wex += wsum[0];
    if (w > 1) wex += wsum[1];
    if (w > 2) wex += wsum[2];
    int excl = wex + ss - s;

    const int r0 = b << BSH;
    int r = r0 + 2 * t;
    if (r < N)     { offs[r]     = base + excl;      counts[r]     = a0; }
    if (r + 1 < N) { offs[r + 1] = base + excl + a0; counts[r + 1] = a1; }
    lofs[2 * t]     = excl;
    lofs[2 * t + 1] = excl + a0;
    __syncthreads();

    for (int i = t; i < nb; i += 256) {
        int2 p = packed[base + i];
        int lr = ((unsigned)p.x) >> 17;
        int pos = base + atomicAdd(&lofs[lr], 1);
        int2 o;
        o.x = p.x & 0x1FFFF;
        o.y = p.y;
        cv[pos] = o;
    }
}

// ------- SpMM: wave per row, 8-wide unrolled gathers, NT cv loads + NT out stores -------
__global__ __launch_bounds__(256) void spmm_kernel(const unsigned short* __restrict__ S,
                                                   const int* __restrict__ offs,
                                                   const int* __restrict__ counts,
                                                   const int2* __restrict__ cv,
                                                   const float* __restrict__ bias,
                                                   float* __restrict__ out, int N) {
    const int lane = threadIdx.x & 63;
    const int r = blockIdx.x * 4 + (threadIdx.x >> 6);
    if (r >= N) return;
    const char* Sb = reinterpret_cast<const char*>(S);
    const unsigned long long* cve = reinterpret_cast<const unsigned long long*>(cv);

    float4 acc = { 0.f, 0.f, 0.f, 0.f };
    int i = offs[r];
    const int end = i + counts[r];

#define LOADE(k) __builtin_nontemporal_load(cve + (k))
#define GATHER(e)                                                                 \
    {                                                                             \
        unsigned c = (unsigned)((e) & 0xffffffffu);                               \
        float v = as_f((unsigned)((e) >> 32));                                    \
        uint2 sv = *reinterpret_cast<const uint2*>(Sb + ((size_t)c << 9) + (lane << 3)); \
        acc.x += v * as_f(sv.x << 16);                                            \
        acc.y += v * as_f(sv.x & 0xffff0000u);                                    \
        acc.z += v * as_f(sv.y << 16);                                            \
        acc.w += v * as_f(sv.y & 0xffff0000u);                                    \
    }

    for (; i + 7 < end; i += 8) {
        unsigned long long e0 = LOADE(i),     e1 = LOADE(i + 1);
        unsigned long long e2 = LOADE(i + 2), e3 = LOADE(i + 3);
        unsigned long long e4 = LOADE(i + 4), e5 = LOADE(i + 5);
        unsigned long long e6 = LOADE(i + 6), e7 = LOADE(i + 7);
        GATHER(e0); GATHER(e1); GATHER(e2); GATHER(e3);
        GATHER(e4); GATHER(e5); GATHER(e6); GATHER(e7);
    }
    for (; i + 1 < end; i += 2) {
        unsigned long long e0 = LOADE(i), e1 = LOADE(i + 1);
        GATHER(e0); GATHER(e1);
    }
    if (i < end) {
        unsigned long long e0 = LOADE(i);
        GATHER(e0);
    }
#undef GATHER
#undef LOADE

    float4 b = reinterpret_cast<const float4*>(bias)[lane];
    f32x4 o = { acc.x + b.x, acc.y + b.y, acc.z + b.z, acc.w + b.w };
    __builtin_nontemporal_store(o, reinterpret_cast<f32x4*>(out) + (size_t)r * 64 + lane);
}

extern "C" void kernel_launch(void* const* d_in, const int* in_sizes, int n_in,
                              void* d_out, int out_size, void* d_ws, size_t ws_size,
                              hipStream_t stream) {
    const float* X     = (const float*)d_in[0];
    const float* W     = (const float*)d_in[1];
    const float* bias  = (const float*)d_in[2];
    const float* evals = (const float*)d_in[3];
    const int*   erow  = (const int*)d_in[4];
    const int*   ecol  = (const int*)d_in[5];
    float* out = (float*)d_out;

    const int N = in_sizes[0] / D;
    const int E = in_sizes[3];
    const int NB = ((N - 1) >> BSH) + 1;

    char* ws = (char*)d_ws;
    size_t off = 0;
    auto alloc = [&](size_t bytes) {
        void* p = ws + off;
        off += (bytes + 255) & ~(size_t)255;
        return p;
    };
    unsigned short* S  = (unsigned short*)alloc((size_t)N * D * sizeof(unsigned short));
    unsigned short* Wt = (unsigned short*)alloc((size_t)D * D * sizeof(unsigned short));
    int* bcounts = (int*)alloc((size_t)NB * sizeof(int));
    int* boffs   = (int*)alloc((size_t)NB * sizeof(int));
    int* bcursor = (int*)alloc((size_t)NB * sizeof(int));
    int* offs    = (int*)alloc((size_t)N * sizeof(int));
    int* counts  = (int*)alloc((size_t)N * sizeof(int));
    int2* packed = (int2*)alloc((size_t)E * sizeof(int2));
    int2* cv     = (int2*)alloc((size_t)E * sizeof(int2));

    // 1. Wt = bf16(W^T), zero bcounts
    wt_kernel<<<(D * D) / 256, 256, 0, stream>>>(W, Wt, bcounts, NB);
    // 2. S = bf16(X @ W) via MFMA, bucket histogram fused in epilogue
    gemm_mfma<<<(N + GBM - 1) / GBM, 1024, 0, stream>>>(X, Wt, S, N, erow, bcounts, E, NB);
    // 3. two-phase CSR build
    bscan_kernel<<<1, 1024, 0, stream>>>(bcounts, boffs, bcursor, NB);
    partition_kernel<<<(E + TILE - 1) / TILE, 256, 0, stream>>>(erow, ecol, evals, bcursor,
                                                                packed, E, NB);
    bucket_scatter<<<NB, 256, 0, stream>>>(packed, boffs, bcounts, offs, counts, cv, N);
    // 4. SpMM + bias (NT edge loads, NT out stores)
    spmm_kernel<<<(N + 3) / 4, 256, 0, stream>>>(S, offs, counts, cv, bias, out, N);
}

// Round 12
// 351.624 us; speedup vs baseline: 15.4390x; 1.0796x over previous
//
#include <hip/hip_runtime.h>

#define D 256
#define GBM 256          // gemm rows per block (16 waves x 16)
#define WT_PITCH 264     // bf16 elements per LDS row (256 + 8 pad)
#define BSH 9            // bucket shift: 512 rows per bucket
#define RPB 512          // rows per bucket
#define NBMAX 256        // max buckets (N <= 131072)
#define TILE 4096        // edges per partition block

using bf16x8 = __attribute__((ext_vector_type(8))) short;
using f32x4  = __attribute__((ext_vector_type(4))) float;

static __device__ __forceinline__ unsigned short f2bf(float f) {
    unsigned u = __builtin_bit_cast(unsigned, f);
    return (unsigned short)((u + 0x7fffu + ((u >> 16) & 1u)) >> 16);  // RNE
}
static __device__ __forceinline__ float as_f(unsigned u) {
    return __builtin_bit_cast(float, u);
}

// -------- W transpose + bf16 cast (+ zero bcounts): Wt[n][k] = bf16(W[k][n]) --------
__global__ void wt_kernel(const float* __restrict__ W, unsigned short* __restrict__ Wt,
                          int* __restrict__ bcounts, int NB) {
    int idx = blockIdx.x * blockDim.x + threadIdx.x;
    int n = idx & 255, k = idx >> 8;
    Wt[n * 256 + k] = f2bf(W[k * 256 + n]);
    if (blockIdx.x == 0 && threadIdx.x < NB) bcounts[threadIdx.x] = 0;
}

// ---- GEMM: S(bf16) = X @ W via MFMA, full Wt in LDS; bucket histogram fused ----
__global__ __launch_bounds__(1024) void gemm_mfma(const float* __restrict__ X,
                                                  const unsigned short* __restrict__ Wt,
                                                  unsigned short* __restrict__ S, int N,
                                                  const int* __restrict__ erow,
                                                  int* __restrict__ bcounts,
                                                  int E, int NB) {
    __shared__ unsigned short wlds[256 * WT_PITCH];    // 132 KB
    __shared__ int lh[NBMAX];                          // +1 KB for fused hist

    for (int c = threadIdx.x; c < 8192; c += 1024) {
        int n = c >> 5, kc = c & 31;
        uint4 v = *reinterpret_cast<const uint4*>(Wt + n * 256 + kc * 8);
        *reinterpret_cast<uint4*>(&wlds[n * WT_PITCH + kc * 8]) = v;
    }
    for (int i = threadIdx.x; i < NB; i += 1024) lh[i] = 0;
    __syncthreads();

    const int lane = threadIdx.x & 63;
    const int wave = threadIdx.x >> 6;
    const int row0 = blockIdx.x * GBM + wave * 16;
    const int l16  = lane & 15;
    const int kgrp = lane >> 4;
    const int arow = min(row0 + l16, N - 1);
    const float* xp = X + (size_t)arow * 256 + kgrp * 8;

    f32x4 acc[16];
#pragma unroll
    for (int i = 0; i < 16; i++) acc[i] = (f32x4)(0.0f);

#pragma unroll
    for (int ks = 0; ks < 8; ks++) {
        f32x4 a0 = __builtin_nontemporal_load(reinterpret_cast<const f32x4*>(xp + ks * 32));
        f32x4 a1 = __builtin_nontemporal_load(reinterpret_cast<const f32x4*>(xp + ks * 32 + 4));
        bf16x8 af;
        af[0] = (short)f2bf(a0[0]); af[1] = (short)f2bf(a0[1]);
        af[2] = (short)f2bf(a0[2]); af[3] = (short)f2bf(a0[3]);
        af[4] = (short)f2bf(a1[0]); af[5] = (short)f2bf(a1[1]);
        af[6] = (short)f2bf(a1[2]); af[7] = (short)f2bf(a1[3]);
#pragma unroll
        for (int nt = 0; nt < 16; nt++) {
            bf16x8 bf = *reinterpret_cast<const bf16x8*>(
                &wlds[(nt * 16 + l16) * WT_PITCH + ks * 32 + kgrp * 8]);
            acc[nt] = __builtin_amdgcn_mfma_f32_16x16x32_bf16(af, bf, acc[nt], 0, 0, 0);
        }
    }

    // C/D layout: col = lane&15, row = (lane>>4)*4 + reg
#pragma unroll
    for (int nt = 0; nt < 16; nt++) {
#pragma unroll
        for (int j = 0; j < 4; j++) {
            int r = row0 + kgrp * 4 + j;
            if (r < N) S[(size_t)r * 256 + nt * 16 + l16] = f2bf(acc[nt][j]);
        }
    }

    // ---- fused bucket histogram (hidden under gemm's memory phase) ----
    const int stride = gridDim.x * 1024;
    for (int e = blockIdx.x * 1024 + threadIdx.x; e < E; e += stride)
        atomicAdd(&lh[erow[e] >> BSH], 1);
    __syncthreads();
    for (int i = threadIdx.x; i < NB; i += 1024) {
        int v = lh[i];
        if (v) atomicAdd(&bcounts[i], v);
    }
}

// ---------------- bucket scan (NB <= 1024, single block) ----------------
__global__ __launch_bounds__(1024) void bscan_kernel(const int* __restrict__ bcounts,
                                                     int* __restrict__ boffs,
                                                     int* __restrict__ bcursor, int NB) {
    __shared__ int wsum[16];
    const int t = threadIdx.x, lane = t & 63, w = t >> 6;
    int x = (t < NB) ? bcounts[t] : 0;
    int s = x;
#pragma unroll
    for (int d = 1; d < 64; d <<= 1) {
        int y = __shfl_up(s, d);
        if (lane >= d) s += y;
    }
    if (lane == 63) wsum[w] = s;
    __syncthreads();
    if (w == 0) {
        int ws = (lane < 16) ? wsum[lane] : 0;
#pragma unroll
        for (int d = 1; d < 16; d <<= 1) {
            int y = __shfl_up(ws, d);
            if (lane >= d) ws += y;
        }
        if (lane < 16) wsum[lane] = ws;
    }
    __syncthreads();
    int excl = (w ? wsum[w - 1] : 0) + s - x;
    if (t < NB) { boffs[t] = excl; bcursor[t] = excl; }
}

// ---------------- partition: per-block bulk reservation, rank in LDS ----------------
__global__ __launch_bounds__(256) void partition_kernel(const int* __restrict__ rows,
                                                        const int* __restrict__ cols,
                                                        const float* __restrict__ vals,
                                                        int* __restrict__ bcursor,
                                                        int2* __restrict__ packed,
                                                        int E, int NB) {
    __shared__ int lh[NBMAX];
    __shared__ int gbase[NBMAX];
    const int t = threadIdx.x;
    const int e0 = blockIdx.x * TILE;

    for (int i = t; i < NB; i += 256) lh[i] = 0;
    __syncthreads();

    int bk[16], rk[16], pc[16], pv[16];
#pragma unroll
    for (int j = 0; j < 16; j++) {
        int idx = e0 + j * 256 + t;
        if (idx < E) {
            int r = rows[idx];
            bk[j] = r >> BSH;
            rk[j] = atomicAdd(&lh[bk[j]], 1);
            pc[j] = ((r & (RPB - 1)) << 17) | cols[idx];
            pv[j] = __float_as_int(vals[idx]);
        } else {
            bk[j] = -1;
        }
    }
    __syncthreads();

    for (int i = t; i < NB; i += 256) {
        int c = lh[i];
        gbase[i] = c ? atomicAdd(&bcursor[i], c) : 0;
    }
    __syncthreads();

#pragma unroll
    for (int j = 0; j < 16; j++) {
        if (bk[j] >= 0) {
            int2 p; p.x = pc[j]; p.y = pv[j];
            packed[(size_t)gbase[bk[j]] + rk[j]] = p;
        }
    }
}

// ------- per-bucket counting sort by localrow -> CSR (+offs/counts), 512 thr -------
__global__ __launch_bounds__(512) void bucket_scatter(const int2* __restrict__ packed,
                                                      const int* __restrict__ boffs,
                                                      const int* __restrict__ bcounts,
                                                      int* __restrict__ offs,
                                                      int* __restrict__ counts,
                                                      int2* __restrict__ cv, int N) {
    __shared__ int cnt[RPB];
    __shared__ int lofs[RPB];
    __shared__ int wsum[8];
    const int b = blockIdx.x, t = threadIdx.x;
    const int base = boffs[b], nb = bcounts[b];
    const int lane = t & 63, w = t >> 6;

    cnt[t] = 0;
    __syncthreads();
    for (int i = t; i < nb; i += 512)
        atomicAdd(&cnt[((unsigned)packed[base + i].x) >> 17], 1);
    __syncthreads();

    // exclusive scan over 512 counters, one per thread
    int x = cnt[t];
    int s = x;
#pragma unroll
    for (int d = 1; d < 64; d <<= 1) {
        int y = __shfl_up(s, d);
        if (lane >= d) s += y;
    }
    if (lane == 63) wsum[w] = s;
    __syncthreads();
    if (w == 0) {
        int ws = (lane < 8) ? wsum[lane] : 0;
#pragma unroll
        for (int d = 1; d < 8; d <<= 1) {
            int y = __shfl_up(ws, d);
            if (lane >= d) ws += y;
        }
        if (lane < 8) wsum[lane] = ws;
    }
    __syncthreads();
    int excl = (w ? wsum[w - 1] : 0) + s - x;

    const int r0 = b << BSH;
    int r = r0 + t;
    if (r < N) { offs[r] = base + excl; counts[r] = x; }
    lofs[t] = excl;
    __syncthreads();

    for (int i = t; i < nb; i += 512) {
        int2 p = packed[base + i];
        int lr = ((unsigned)p.x) >> 17;
        int pos = base + atomicAdd(&lofs[lr], 1);
        int2 o;
        o.x = p.x & 0x1FFFF;
        o.y = p.y;
        cv[pos] = o;
    }
}

// ------- SpMM: wave per row, 8-wide unrolled bf16 gathers (R6, proven 222 us) -------
__global__ __launch_bounds__(256) void spmm_kernel(const unsigned short* __restrict__ S,
                                                   const int* __restrict__ offs,
                                                   const int* __restrict__ counts,
                                                   const int2* __restrict__ cv,
                                                   const float* __restrict__ bias,
                                                   float* __restrict__ out, int N) {
    const int lane = threadIdx.x & 63;
    const int r = blockIdx.x * 4 + (threadIdx.x >> 6);
    if (r >= N) return;
    const char* Sb = reinterpret_cast<const char*>(S);

    float4 acc = { 0.f, 0.f, 0.f, 0.f };
    int i = offs[r];
    const int end = i + counts[r];

#define GATHER(c, v)                                                              \
    {                                                                             \
        uint2 sv = *reinterpret_cast<const uint2*>(Sb + ((size_t)(c) << 9) + (lane << 3)); \
        acc.x += (v) * as_f(sv.x << 16);                                          \
        acc.y += (v) * as_f(sv.x & 0xffff0000u);                                  \
        acc.z += (v) * as_f(sv.y << 16);                                          \
        acc.w += (v) * as_f(sv.y & 0xffff0000u);                                  \
    }

    for (; i + 7 < end; i += 8) {
        int2 e0 = cv[i],     e1 = cv[i + 1], e2 = cv[i + 2], e3 = cv[i + 3];
        int2 e4 = cv[i + 4], e5 = cv[i + 5], e6 = cv[i + 6], e7 = cv[i + 7];
        GATHER(e0.x, as_f((unsigned)e0.y));
        GATHER(e1.x, as_f((unsigned)e1.y));
        GATHER(e2.x, as_f((unsigned)e2.y));
        GATHER(e3.x, as_f((unsigned)e3.y));
        GATHER(e4.x, as_f((unsigned)e4.y));
        GATHER(e5.x, as_f((unsigned)e5.y));
        GATHER(e6.x, as_f((unsigned)e6.y));
        GATHER(e7.x, as_f((unsigned)e7.y));
    }
    for (; i + 1 < end; i += 2) {
        int2 e0 = cv[i], e1 = cv[i + 1];
        GATHER(e0.x, as_f((unsigned)e0.y));
        GATHER(e1.x, as_f((unsigned)e1.y));
    }
    if (i < end) {
        int2 e0 = cv[i];
        GATHER(e0.x, as_f((unsigned)e0.y));
    }
#undef GATHER

    float4 b = reinterpret_cast<const float4*>(bias)[lane];
    float4 o = { acc.x + b.x, acc.y + b.y, acc.z + b.z, acc.w + b.w };
    reinterpret_cast<float4*>(out)[(size_t)r * 64 + lane] = o;
}

extern "C" void kernel_launch(void* const* d_in, const int* in_sizes, int n_in,
                              void* d_out, int out_size, void* d_ws, size_t ws_size,
                              hipStream_t stream) {
    const float* X     = (const float*)d_in[0];
    const float* W     = (const float*)d_in[1];
    const float* bias  = (const float*)d_in[2];
    const float* evals = (const float*)d_in[3];
    const int*   erow  = (const int*)d_in[4];
    const int*   ecol  = (const int*)d_in[5];
    float* out = (float*)d_out;

    const int N = in_sizes[0] / D;
    const int E = in_sizes[3];
    const int NB = ((N - 1) >> BSH) + 1;

    char* ws = (char*)d_ws;
    size_t off = 0;
    auto alloc = [&](size_t bytes) {
        void* p = ws + off;
        off += (bytes + 255) & ~(size_t)255;
        return p;
    };
    unsigned short* S  = (unsigned short*)alloc((size_t)N * D * sizeof(unsigned short));
    unsigned short* Wt = (unsigned short*)alloc((size_t)D * D * sizeof(unsigned short));
    int* bcounts = (int*)alloc((size_t)NB * sizeof(int));
    int* boffs   = (int*)alloc((size_t)NB * sizeof(int));
    int* bcursor = (int*)alloc((size_t)NB * sizeof(int));
    int* offs    = (int*)alloc((size_t)N * sizeof(int));
    int* counts  = (int*)alloc((size_t)N * sizeof(int));
    int2* packed = (int2*)alloc((size_t)E * sizeof(int2));
    int2* cv     = (int2*)alloc((size_t)E * sizeof(int2));

    // 1. Wt = bf16(W^T), zero bcounts
    wt_kernel<<<(D * D) / 256, 256, 0, stream>>>(W, Wt, bcounts, NB);
    // 2. S = bf16(X @ W) via MFMA, bucket histogram fused in epilogue
    gemm_mfma<<<(N + GBM - 1) / GBM, 1024, 0, stream>>>(X, Wt, S, N, erow, bcounts, E, NB);
    // 3. two-phase CSR build
    bscan_kernel<<<1, 1024, 0, stream>>>(bcounts, boffs, bcursor, NB);
    partition_kernel<<<(E + TILE - 1) / TILE, 256, 0, stream>>>(erow, ecol, evals, bcursor,
                                                                packed, E, NB);
    bucket_scatter<<<NB, 512, 0, stream>>>(packed, boffs, bcounts, offs, counts, cv, N);
    // 4. SpMM + bias (R6 flat loop, 8 gathers in flight)
    spmm_kernel<<<(N + 3) / 4, 256, 0, stream>>>(S, offs, counts, cv, bias, out, N);
}